// Round 2
// baseline (150.239 us; speedup 1.0000x reference)
//
#include <hip/hip_runtime.h>

// out[g,i,j,:] = sum(edge_attr over edges (i->j) in g)  [unique edges -> overwrite]
//             + emb_table[1] on in-graph diagonal, emb_table[2] if no edge/off-graph,
//               0 extra at edge positions (A=0 -> padding row of emb is zero).
//
// Strategy: per-source-node CSR in ws, then one block per output row:
// stream background (emb1/emb2), barrier, overwrite edge cells (L2-merge).

// ---------------- CSR prep ----------------

__global__ void zero_kernel(int* __restrict__ ws, int beg, int end) {
    int i = beg + blockIdx.x * blockDim.x + threadIdx.x;
    int stride = gridDim.x * blockDim.x;
    for (; i < end; i += stride) ws[i] = 0;
}

__global__ void hist_kernel(const int* __restrict__ batch, const int* __restrict__ eidx,
                            int* __restrict__ ws, int B, int TN, int E) {
    int* counts = ws + B;
    int* rowcnt = ws + 2 * B + TN + 1;
    int idx = blockIdx.x * blockDim.x + threadIdx.x;
    int stride = gridDim.x * blockDim.x;
    for (int v = idx; v < TN; v += stride) atomicAdd(&counts[batch[v]], 1);
    for (int e = idx; e < E; e += stride) atomicAdd(&rowcnt[eidx[e]], 1);
}

__global__ __launch_bounds__(1024) void scan_kernel(int* __restrict__ ws, int B, int TN) {
    int* offs   = ws;
    int* counts = ws + B;
    int* rowoff = ws + 2 * B;
    int* rowcnt = ws + 2 * B + TN + 1;
    __shared__ int part[1024];
    int tid = threadIdx.x;
    int nb  = (int)blockDim.x;
    int chunk = (TN + nb - 1) / nb;
    int s0 = tid * chunk;
    int s1 = min(s0 + chunk, TN);
    int sum = 0;
    for (int r = s0; r < s1; ++r) sum += rowcnt[r];
    part[tid] = sum;
    __syncthreads();
    for (int off = 1; off < nb; off <<= 1) {
        int v = (tid >= off) ? part[tid - off] : 0;
        __syncthreads();
        if (tid >= off) part[tid] += v;
        __syncthreads();
    }
    int excl = (tid == 0) ? 0 : part[tid - 1];
    for (int r = s0; r < s1; ++r) { rowoff[r] = excl; excl += rowcnt[r]; }
    if (s1 == TN) rowoff[TN] = excl;   // threads past the end all write the same total
    if (tid == 0) {
        int acc = 0;
        for (int g = 0; g < B; ++g) { offs[g] = acc; acc += counts[g]; }
    }
}

__global__ void scatter_kernel(const int* __restrict__ eidx, int* __restrict__ ws,
                               int2* __restrict__ elist, int B, int TN, int E) {
    const int* rowoff = ws + 2 * B;
    int* rowcur = ws + 2 * B + 2 * TN + 1;
    int idx = blockIdx.x * blockDim.x + threadIdx.x;
    int stride = gridDim.x * blockDim.x;
    for (int e = idx; e < E; e += stride) {
        int s = eidx[e];
        int pos = atomicAdd(&rowcur[s], 1);
        elist[rowoff[s] + pos] = make_int2(eidx[E + e], e);  // (global dst, edge id)
    }
}

// ---------------- fused fill + edge overwrite ----------------
// One block per output row (g,i). Background is a pure 32KB stream;
// edge overwrite hits lines this block just wrote (L2-resident -> merge).

__global__ __launch_bounds__(256) void fused_kernel(
        const float4* __restrict__ attr, const float4* __restrict__ emb,
        const int2* __restrict__ elist, const int* __restrict__ ws,
        float4* __restrict__ out, int B, int N, int D4, int lg) {
    const int* offs   = ws;
    const int* counts = ws + B;
    const int* rowoff = ws + 2 * B;

    int bid = blockIdx.x;            // g*N + i
    int g = bid / N;
    int i = bid - g * N;
    int cnt = counts[g];
    int off = offs[g];
    bool real = (i < cnt);
    int kbeg = 0, kend = 0;
    if (real) {
        int s = off + i;
        kbeg = rowoff[s];
        kend = rowoff[s + 1];
    }
    int k = kend - kbeg;
    if (k > 1024) k = 1024;          // cap (unique edges -> k <= N, always fits)

    __shared__ int2 lds[1024];
    for (int m = threadIdx.x; m < k; m += blockDim.x) {
        int2 v = elist[kbeg + m];
        lds[m] = make_int2(v.x - off, v.y);   // (local dst j, edge id)
    }
    __syncthreads();

    int d4 = threadIdx.x & (D4 - 1);
    int j0 = threadIdx.x >> lg;
    int jStep = (int)blockDim.x >> lg;
    float4 v1 = emb[D4 + d4];        // emb_table[1]
    float4 v2 = emb[2 * D4 + d4];    // emb_table[2]
    size_t outBase = (size_t)bid * ((size_t)N << lg);

    // background: fully sequential row stream
    for (int j = j0; j < N; j += jStep) {
        float4 val = (real && j == i) ? v1 : v2;
        out[outBase + ((size_t)j << lg) + d4] = val;
    }
    __syncthreads();   // drains stores (vmcnt) before overwrite by other threads

    // edge overwrite: k*D4 units, lines still in L2
    int units = k << lg;
    for (int t = threadIdx.x; t < units; t += blockDim.x) {
        int m  = t >> lg;
        int dd = t & (D4 - 1);
        int2 ed = lds[m];
        float4 a = attr[((size_t)ed.y << lg) + dd];
        out[outBase + ((size_t)ed.x << lg) + dd] = a;
    }
}

// ---------------- fallback (small ws): previous 3-kernel version ----------------

__global__ void prep_kernel(const int* __restrict__ batch, int* __restrict__ ws,
                            int TN, int B) {
    extern __shared__ int cnt[];
    for (int i = threadIdx.x; i < B; i += blockDim.x) cnt[i] = 0;
    __syncthreads();
    for (int v = threadIdx.x; v < TN; v += blockDim.x)
        atomicAdd(&cnt[batch[v]], 1);
    __syncthreads();
    if (threadIdx.x == 0) {
        int acc = 0;
        for (int g = 0; g < B; ++g) {
            int c = cnt[g];
            ws[g] = acc; ws[B + g] = c; acc += c;
        }
    }
}

__global__ void fill_kernel(float4* __restrict__ out, const float4* __restrict__ emb,
                            const int* __restrict__ counts, int N, int D4, int jPer) {
    int g  = blockIdx.z;
    int i  = blockIdx.y;
    int d4 = threadIdx.x % D4;
    int jj = threadIdx.x / D4;
    int j  = blockIdx.x * jPer + jj;
    if (j >= N) return;
    float4 v1 = emb[D4 + d4];
    float4 v2 = emb[2 * D4 + d4];
    bool diag = (j == i) && (i < counts[g]);
    float4 v = diag ? v1 : v2;
    size_t row = (size_t)(g * N + i);
    out[(row * N + j) * D4 + d4] = v;
}

__global__ void edge_kernel(const float4* __restrict__ attr, const int* __restrict__ eidx,
                            const int* __restrict__ batch, const int* __restrict__ offs,
                            float4* __restrict__ out, int E, int N, int D4) {
    int idx = blockIdx.x * blockDim.x + threadIdx.x;
    if (idx >= E * D4) return;
    int e  = idx / D4;
    int d4 = idx - e * D4;
    int s  = eidx[e];
    int d  = eidx[E + e];
    int g  = batch[s];
    int off = offs[g];
    out[(((size_t)g * N + (s - off)) * N + (d - off)) * D4 + d4] =
        attr[(size_t)e * D4 + d4];
}

extern "C" void kernel_launch(void* const* d_in, const int* in_sizes, int n_in,
                              void* d_out, int out_size, void* d_ws, size_t ws_size,
                              hipStream_t stream) {
    const float* edge_attr  = (const float*)d_in[0];
    const float* emb_table  = (const float*)d_in[1];
    const int*   edge_index = (const int*)d_in[2];
    const int*   batch_vec  = (const int*)d_in[3];

    int D  = in_sizes[1] / 3;
    int E  = in_sizes[2] / 2;
    int TN = in_sizes[3];
    int D4 = D / 4;
    int N  = (int)((long long)out_size / ((long long)TN * (long long)D));
    int B  = TN / N;

    int lg = 0;
    while ((1 << lg) < D4) ++lg;
    bool pow2 = ((1 << lg) == D4) && (D4 >= 1) && (D4 <= 256) && (D % 4 == 0);

    float* out = (float*)d_out;
    int*   ws  = (int*)d_ws;

    // ws int layout: offs[B] | counts[B] | rowoff[TN+1] | rowcnt[TN] | rowcur[TN] | elist int2[E]
    long long intHdr = 2LL * B + 3LL * TN + 1;
    long long eoffInt = (intHdr + 1) & ~1LL;                 // 8B-align elist
    long long needBytes = eoffInt * 4 + (long long)E * 8;

    if (pow2 && (long long)ws_size >= needBytes) {
        int2* elist = (int2*)(ws + eoffInt);
        int zEnd = (int)intHdr;

        zero_kernel<<<64, 256, 0, stream>>>(ws, B, zEnd);
        hist_kernel<<<256, 256, 0, stream>>>(batch_vec, edge_index, ws, B, TN, E);
        scan_kernel<<<1, 1024, 0, stream>>>(ws, B, TN);
        scatter_kernel<<<256, 256, 0, stream>>>(edge_index, ws, elist, B, TN, E);
        fused_kernel<<<B * N, 256, 0, stream>>>((const float4*)edge_attr,
                                                (const float4*)emb_table, elist, ws,
                                                (float4*)out, B, N, D4, lg);
    } else {
        // fallback: 3-kernel overwrite version (needs only 2B ints of ws)
        prep_kernel<<<1, 1024, (size_t)B * sizeof(int), stream>>>(batch_vec, ws, TN, B);
        int jPer = 256 / D4;
        dim3 fgrid((N + jPer - 1) / jPer, N, B);
        fill_kernel<<<fgrid, 256, 0, stream>>>((float4*)out, (const float4*)emb_table,
                                               ws + B, N, D4, jPer);
        long long eunits = (long long)E * D4;
        int eblocks = (int)((eunits + 255) / 256);
        edge_kernel<<<eblocks, 256, 0, stream>>>((const float4*)edge_attr, edge_index,
                                                 batch_vec, ws, (float4*)out, E, N, D4);
    }
}

// Round 3
// 80.344 us; speedup vs baseline: 1.8699x; 1.8699x over previous
//
#include <hip/hip_runtime.h>

// out[g,i,j,:] = edge_attr[e] at edge positions (unique, off-diag -> overwrite)
//             + emb_table[1] on in-graph diagonal, emb_table[2] elsewhere.
// Pass 1: flat memset-style fill with emb_table[2] (full-rate store stream).
// Pass 2: overwrite diagonal rows with emb_table[1] (2 MB).
// Pass 3: overwrite edge rows with edge_attr (33.5 MB R + 33.5 MB W).

__global__ void prep_kernel(const int* __restrict__ batch, int* __restrict__ ws,
                            int TN, int B) {
    // ws: [0,B) exclusive offsets, [B,2B) counts
    extern __shared__ int cnt[];
    for (int i = threadIdx.x; i < B; i += blockDim.x) cnt[i] = 0;
    __syncthreads();
    for (int v = threadIdx.x; v < TN; v += blockDim.x)
        atomicAdd(&cnt[batch[v]], 1);
    __syncthreads();
    if (threadIdx.x == 0) {
        int acc = 0;
        for (int g = 0; g < B; ++g) {
            int c = cnt[g];
            ws[g] = acc; ws[B + g] = c; acc += c;
        }
    }
}

// Memset-shaped: flat grid-stride, value loop-invariant per thread
// (requires grid stride divisible by D4 -> D4 pow2 <= 256 with 256-thr blocks).
__global__ __launch_bounds__(256) void fill_flat(float4* __restrict__ out,
                                                 const float4* __restrict__ emb,
                                                 long long total4, int D4, int mask) {
    long long idx = (long long)blockIdx.x * blockDim.x + threadIdx.x;
    long long stride = (long long)gridDim.x * blockDim.x;
    float4 v2 = emb[2 * D4 + (int)(idx & mask)];
    for (; idx < total4; idx += stride) out[idx] = v2;
}

// Generic fallback fill (non-pow2 D4)
__global__ void fill_generic(float4* __restrict__ out, const float4* __restrict__ emb,
                             long long total4, int D4) {
    long long idx = (long long)blockIdx.x * blockDim.x + threadIdx.x;
    long long stride = (long long)gridDim.x * blockDim.x;
    for (; idx < total4; idx += stride)
        out[idx] = emb[2 * D4 + (int)(idx % D4)];
}

__global__ void diag_kernel(float4* __restrict__ out, const float4* __restrict__ emb,
                            const int* __restrict__ counts, int N, int D4, int total) {
    int idx = blockIdx.x * blockDim.x + threadIdx.x;   // over B*N*D4
    if (idx >= total) return;
    int d4  = idx % D4;
    int row = idx / D4;        // g*N + i
    int g = row / N;
    int i = row - g * N;
    if (i >= counts[g]) return;            // pad rows keep emb2 on diag
    out[((size_t)row * N + i) * D4 + d4] = emb[D4 + d4];
}

__global__ void edge_kernel(const float4* __restrict__ attr, const int* __restrict__ eidx,
                            const int* __restrict__ batch, const int* __restrict__ offs,
                            float4* __restrict__ out, int E, int N, int D4) {
    int idx = blockIdx.x * blockDim.x + threadIdx.x;
    if (idx >= E * D4) return;
    int e  = idx / D4;
    int d4 = idx - e * D4;
    int s  = eidx[e];
    int d  = eidx[E + e];
    int g  = batch[s];
    int off = offs[g];
    out[(((size_t)g * N + (s - off)) * N + (d - off)) * D4 + d4] =
        attr[(size_t)e * D4 + d4];
}

extern "C" void kernel_launch(void* const* d_in, const int* in_sizes, int n_in,
                              void* d_out, int out_size, void* d_ws, size_t ws_size,
                              hipStream_t stream) {
    const float* edge_attr  = (const float*)d_in[0];
    const float* emb_table  = (const float*)d_in[1];
    const int*   edge_index = (const int*)d_in[2];
    const int*   batch_vec  = (const int*)d_in[3];

    int D  = in_sizes[1] / 3;                 // emb_table [3, D]
    int E  = in_sizes[2] / 2;                 // edge_index [2, E]
    int TN = in_sizes[3];                     // total nodes
    int D4 = D / 4;
    int N  = (int)((long long)out_size / ((long long)TN * (long long)D));
    int B  = TN / N;

    float* out = (float*)d_out;
    int*   ws  = (int*)d_ws;                  // offs[0..B), counts[B..2B)

    prep_kernel<<<1, 1024, (size_t)B * sizeof(int), stream>>>(batch_vec, ws, TN, B);

    long long total4 = (long long)out_size / 4;     // float4 count
    bool pow2 = (D4 & (D4 - 1)) == 0 && D4 <= 256;
    int fblocks = 2048;
    if (pow2) {
        fill_flat<<<fblocks, 256, 0, stream>>>((float4*)out, (const float4*)emb_table,
                                               total4, D4, D4 - 1);
    } else {
        fill_generic<<<fblocks, 256, 0, stream>>>((float4*)out, (const float4*)emb_table,
                                                  total4, D4);
    }

    int dTotal = B * N * D4;
    diag_kernel<<<(dTotal + 255) / 256, 256, 0, stream>>>((float4*)out,
                                                          (const float4*)emb_table,
                                                          ws + B, N, D4, dTotal);

    long long eunits = (long long)E * D4;
    int eblocks = (int)((eunits + 255) / 256);
    edge_kernel<<<eblocks, 256, 0, stream>>>((const float4*)edge_attr, edge_index,
                                             batch_vec, ws, (float4*)out, E, N, D4);
}

// Round 5
// 76.220 us; speedup vs baseline: 1.9711x; 1.0541x over previous
//
#include <hip/hip_runtime.h>

// out[g,i,j,:] = edge_attr[e] at edge positions (unique, off-diag -> overwrite)
//             + emb_table[1] on in-graph diagonal (i < counts[g]), emb_table[2] elsewhere.
// prep: counts/offsets per graph.  fill4: background+diag, 4 nt-stores/thread,
// 16KB contiguous per block.  edge: coalesced read, row-scatter nt-store.

typedef float f4 __attribute__((ext_vector_type(4)));   // native vector for nt builtins

__global__ void prep_kernel(const int* __restrict__ batch, int* __restrict__ ws,
                            int TN, int B) {
    // ws: [0,B) exclusive offsets, [B,2B) counts
    extern __shared__ int cnt[];
    for (int i = threadIdx.x; i < B; i += blockDim.x) cnt[i] = 0;
    __syncthreads();
    for (int v = threadIdx.x; v < TN; v += blockDim.x)
        atomicAdd(&cnt[batch[v]], 1);
    __syncthreads();
    if (threadIdx.x == 0) {
        int acc = 0;
        for (int g = 0; g < B; ++g) {
            int c = cnt[g];
            ws[g] = acc; ws[B + g] = c; acc += c;
        }
    }
}

// Grid: (ceil(N*D4/1024), N, B). Block writes 4 x 256 consecutive float4
// (16KB) of row (g,i); diag column gets emb1. Non-temporal (stream) stores.
__global__ __launch_bounds__(256) void fill4_kernel(
        f4* __restrict__ out, const f4* __restrict__ emb,
        const int* __restrict__ counts, int N, int D4, int lg, int unitsPerRow) {
    int g = blockIdx.z;
    int i = blockIdx.y;
    int cnt = counts[g];
    bool real = (i < cnt);
    int base = blockIdx.x * 1024 + threadIdx.x;   // float4 unit within row
    int d4 = base & (D4 - 1);
    f4 v1 = emb[D4 + d4];
    f4 v2 = emb[2 * D4 + d4];
    size_t rowBase = (size_t)(g * N + i) * unitsPerRow;
#pragma unroll
    for (int k = 0; k < 4; ++k) {
        int unit = base + k * 256;
        if (unit < unitsPerRow) {
            int j = unit >> lg;
            f4 v = (real && j == i) ? v1 : v2;
            __builtin_nontemporal_store(v, &out[rowBase + unit]);
        }
    }
}

__global__ void edge_kernel(const f4* __restrict__ attr, const int* __restrict__ eidx,
                            const int* __restrict__ batch, const int* __restrict__ offs,
                            f4* __restrict__ out, int E, int N, int D4) {
    int idx = blockIdx.x * blockDim.x + threadIdx.x;
    if (idx >= E * D4) return;
    int e  = idx / D4;
    int d4 = idx - e * D4;
    int s  = eidx[e];
    int d  = eidx[E + e];
    int g  = batch[s];
    int off = offs[g];
    f4 v = attr[(size_t)e * D4 + d4];
    __builtin_nontemporal_store(
        v, &out[(((size_t)g * N + (s - off)) * N + (d - off)) * D4 + d4]);
}

// ---- generic fallback (non-pow2 D4) ----
__global__ void fill_generic(f4* __restrict__ out, const f4* __restrict__ emb,
                             long long total4, int D4) {
    long long idx = (long long)blockIdx.x * blockDim.x + threadIdx.x;
    long long stride = (long long)gridDim.x * blockDim.x;
    for (; idx < total4; idx += stride)
        out[idx] = emb[2 * D4 + (int)(idx % D4)];
}

__global__ void diag_kernel(f4* __restrict__ out, const f4* __restrict__ emb,
                            const int* __restrict__ counts, int N, int D4, int total) {
    int idx = blockIdx.x * blockDim.x + threadIdx.x;   // over B*N*D4
    if (idx >= total) return;
    int d4  = idx % D4;
    int row = idx / D4;
    int g = row / N;
    int i = row - g * N;
    if (i >= counts[g]) return;
    out[((size_t)row * N + i) * D4 + d4] = emb[D4 + d4];
}

extern "C" void kernel_launch(void* const* d_in, const int* in_sizes, int n_in,
                              void* d_out, int out_size, void* d_ws, size_t ws_size,
                              hipStream_t stream) {
    const float* edge_attr  = (const float*)d_in[0];
    const float* emb_table  = (const float*)d_in[1];
    const int*   edge_index = (const int*)d_in[2];
    const int*   batch_vec  = (const int*)d_in[3];

    int D  = in_sizes[1] / 3;                 // emb_table [3, D]
    int E  = in_sizes[2] / 2;                 // edge_index [2, E]
    int TN = in_sizes[3];                     // total nodes
    int D4 = D / 4;
    int N  = (int)((long long)out_size / ((long long)TN * (long long)D));
    int B  = TN / N;

    f4*  out = (f4*)d_out;
    int* ws  = (int*)d_ws;                    // offs[0..B), counts[B..2B)

    prep_kernel<<<1, 1024, (size_t)B * sizeof(int), stream>>>(batch_vec, ws, TN, B);

    bool pow2 = (D4 & (D4 - 1)) == 0 && D4 >= 1 && D4 <= 256 && (D % 4 == 0);
    if (pow2) {
        int lg = 0;
        while ((1 << lg) < D4) ++lg;
        int unitsPerRow = N * D4;
        dim3 fgrid((unitsPerRow + 1023) / 1024, N, B);
        fill4_kernel<<<fgrid, 256, 0, stream>>>(out, (const f4*)emb_table,
                                                ws + B, N, D4, lg, unitsPerRow);
    } else {
        long long total4 = (long long)out_size / 4;
        fill_generic<<<2048, 256, 0, stream>>>(out, (const f4*)emb_table,
                                               total4, D4);
        int dTotal = B * N * D4;
        diag_kernel<<<(dTotal + 255) / 256, 256, 0, stream>>>(
            out, (const f4*)emb_table, ws + B, N, D4, dTotal);
    }

    long long eunits = (long long)E * D4;
    int eblocks = (int)((eunits + 255) / 256);
    edge_kernel<<<eblocks, 256, 0, stream>>>((const f4*)edge_attr, edge_index,
                                             batch_vec, ws, out, E, N, D4);
}

// Round 6
// 75.430 us; speedup vs baseline: 1.9918x; 1.0105x over previous
//
#include <hip/hip_runtime.h>

// out[g,i,j,:] = edge_attr[e] at edge cells, emb_table[1] on in-graph diagonal,
//                emb_table[2] elsewhere (emb row 0 = zeros makes edge cells pure copy).
// K1: block0 -> offs[B+1]; other blocks zero 1-bit-per-cell edge mask (ws).
// K2: set mask bit per edge.
// K3: single dispatch = edge-copy blocks (first) + masked background fill blocks.
//     Disjoint cells -> no ordering needed; each cell is 256B (whole lines), so
//     skipping masked cells really saves HBM store traffic.

typedef float f4 __attribute__((ext_vector_type(4)));

__global__ __launch_bounds__(256) void prep_zero_kernel(
        const int* __restrict__ batch, int* __restrict__ offs,
        f4* __restrict__ mask4, long long mask4N, int TN, int B) {
    if (blockIdx.x == 0) {
        __shared__ int cnt[1024];
        for (int i = threadIdx.x; i < B; i += 256) cnt[i] = 0;
        __syncthreads();
        for (int v = threadIdx.x; v < TN; v += 256)
            atomicAdd(&cnt[batch[v]], 1);
        __syncthreads();
        if (threadIdx.x == 0) {
            int acc = 0;
            for (int g = 0; g < B; ++g) { offs[g] = acc; acc += cnt[g]; }
            offs[B] = acc;
        }
    } else {
        long long idx = (long long)(blockIdx.x - 1) * 256 + threadIdx.x;
        long long stride = (long long)(gridDim.x - 1) * 256;
        f4 z = {0.f, 0.f, 0.f, 0.f};
        for (; idx < mask4N; idx += stride) mask4[idx] = z;
    }
}

__global__ void mask_build_kernel(const int* __restrict__ eidx,
                                  const int* __restrict__ batch,
                                  const int* __restrict__ offs,
                                  unsigned* __restrict__ mask,
                                  int E, int N, int lgN) {
    int e = blockIdx.x * blockDim.x + threadIdx.x;
    if (e >= E) return;
    int s = eidx[e], d = eidx[E + e];
    int g = batch[s];
    int off = offs[g];
    long long cell = (((long long)g << lgN) + (s - off)) * N + (d - off);
    atomicOr(&mask[cell >> 5], 1u << ((int)cell & 31));
}

__global__ __launch_bounds__(256) void main_kernel(
        const f4* __restrict__ attr, const f4* __restrict__ emb,
        const int* __restrict__ eidx, const int* __restrict__ batch,
        const int* __restrict__ offs, const unsigned* __restrict__ mask,
        f4* __restrict__ out,
        int E, int N, int D4, int lg, int lgN, int lgCPR, int eBlocks) {
    int bid = blockIdx.x;
    if (bid < eBlocks) {
        // ---- edge copy: coalesced read, 256B-row scatter write ----
        long long idx = (long long)bid * 256 + threadIdx.x;
        if (idx < ((long long)E << lg)) {
            int e  = (int)(idx >> lg);
            int d4 = (int)idx & (D4 - 1);
            int s = eidx[e], d = eidx[E + e];
            int g = batch[s];
            int off = offs[g];
            size_t row = ((size_t)g << lgN) + (s - off);
            out[(row * N + (d - off)) * D4 + d4] = attr[((size_t)e << lg) + d4];
        }
    } else {
        // ---- background fill: 256 consecutive float4 per block, mask-skipped ----
        int fb   = bid - eBlocks;
        int chunk = fb & ((1 << lgCPR) - 1);
        int rowi  = fb >> lgCPR;              // g*N + i
        int i = rowi & (N - 1);
        int g = rowi >> lgN;
        int o0 = offs[g], o1 = offs[g + 1];
        bool real = (i < o1 - o0);
        int unit = (chunk << 8) + threadIdx.x;   // float4 unit within row
        int j  = unit >> lg;
        int d4 = unit & (D4 - 1);
        f4 v = (real && j == i) ? emb[D4 + d4] : emb[2 * D4 + d4];
        long long cell = ((long long)rowi << lgN) + j;
        unsigned bit = (mask[cell >> 5] >> ((int)cell & 31)) & 1u;
        if (!bit)
            out[((size_t)rowi << (lgN + lg)) + unit] = v;
    }
}

// ---------------- fallback (R1 structure, plain stores) ----------------

__global__ void prep_kernel(const int* __restrict__ batch, int* __restrict__ ws,
                            int TN, int B) {
    extern __shared__ int cnt[];
    for (int i = threadIdx.x; i < B; i += blockDim.x) cnt[i] = 0;
    __syncthreads();
    for (int v = threadIdx.x; v < TN; v += blockDim.x)
        atomicAdd(&cnt[batch[v]], 1);
    __syncthreads();
    if (threadIdx.x == 0) {
        int acc = 0;
        for (int g = 0; g < B; ++g) {
            int c = cnt[g];
            ws[g] = acc; ws[B + g] = c; acc += c;
        }
    }
}

__global__ void fill_kernel(f4* __restrict__ out, const f4* __restrict__ emb,
                            const int* __restrict__ counts, int N, int D4, int jPer) {
    int g  = blockIdx.z;
    int i  = blockIdx.y;
    int d4 = threadIdx.x % D4;
    int jj = threadIdx.x / D4;
    int j  = blockIdx.x * jPer + jj;
    if (j >= N) return;
    f4 v1 = emb[D4 + d4];
    f4 v2 = emb[2 * D4 + d4];
    bool diag = (j == i) && (i < counts[g]);
    f4 v = diag ? v1 : v2;
    size_t row = (size_t)(g * N + i);
    out[(row * N + j) * D4 + d4] = v;
}

__global__ void edge_kernel(const f4* __restrict__ attr, const int* __restrict__ eidx,
                            const int* __restrict__ batch, const int* __restrict__ offs,
                            f4* __restrict__ out, int E, int N, int D4) {
    int idx = blockIdx.x * blockDim.x + threadIdx.x;
    if (idx >= E * D4) return;
    int e  = idx / D4;
    int d4 = idx - e * D4;
    int s  = eidx[e];
    int d  = eidx[E + e];
    int g  = batch[s];
    int off = offs[g];
    out[(((size_t)g * N + (s - off)) * N + (d - off)) * D4 + d4] =
        attr[(size_t)e * D4 + d4];
}

extern "C" void kernel_launch(void* const* d_in, const int* in_sizes, int n_in,
                              void* d_out, int out_size, void* d_ws, size_t ws_size,
                              hipStream_t stream) {
    const float* edge_attr  = (const float*)d_in[0];
    const float* emb_table  = (const float*)d_in[1];
    const int*   edge_index = (const int*)d_in[2];
    const int*   batch_vec  = (const int*)d_in[3];

    int D  = in_sizes[1] / 3;                 // emb_table [3, D]
    int E  = in_sizes[2] / 2;                 // edge_index [2, E]
    int TN = in_sizes[3];                     // total nodes
    int D4 = D / 4;
    int N  = (int)((long long)out_size / ((long long)TN * (long long)D));
    int B  = TN / N;

    f4*  out = (f4*)d_out;
    int* ws  = (int*)d_ws;

    auto ispow2 = [](int x) { return x > 0 && (x & (x - 1)) == 0; };
    int lg = 0;  while ((1 << lg) < D4) ++lg;
    int lgN = 0; while ((1 << lgN) < N) ++lgN;
    int unitsRow = N * D4;
    int CPR = unitsRow >> 8;                  // 256-unit chunks per row
    int lgCPR = 0; while ((1 << lgCPR) < CPR) ++lgCPR;

    long long maskWords = ((long long)TN * N) / 32;
    int maskOff = ((B + 1 + 31) / 32) * 32;   // int offset of mask, 128B aligned
    long long needBytes = ((long long)maskOff + maskWords) * 4;

    bool fast = ispow2(D4) && D4 <= 256 && (D % 4 == 0) &&
                ispow2(N) && unitsRow >= 256 && (unitsRow & 255) == 0 &&
                ispow2(CPR) && B <= 1024 &&
                (((long long)TN * N) % 128 == 0) &&
                (long long)ws_size >= needBytes;

    if (fast) {
        int* offs = ws;
        unsigned* mask = (unsigned*)(ws + maskOff);
        long long mask4N = maskWords / 4;

        int zBlocks = (int)((mask4N + 255) / 256);
        prep_zero_kernel<<<1 + zBlocks, 256, 0, stream>>>(batch_vec, offs,
                                                          (f4*)mask, mask4N, TN, B);
        mask_build_kernel<<<(E + 255) / 256, 256, 0, stream>>>(edge_index, batch_vec,
                                                               offs, mask, E, N, lgN);
        long long eUnits = (long long)E << lg;
        int eBlocks = (int)((eUnits + 255) / 256);
        int fillBlocks = TN * CPR;            // B*N rows * CPR chunks
        main_kernel<<<eBlocks + fillBlocks, 256, 0, stream>>>(
            (const f4*)edge_attr, (const f4*)emb_table, edge_index, batch_vec,
            offs, mask, out, E, N, D4, lg, lgN, lgCPR, eBlocks);
    } else {
        prep_kernel<<<1, 1024, (size_t)B * sizeof(int), stream>>>(batch_vec, ws, TN, B);
        int jPer = 256 / D4;
        dim3 fgrid((N + jPer - 1) / jPer, N, B);
        fill_kernel<<<fgrid, 256, 0, stream>>>(out, (const f4*)emb_table,
                                               ws + B, N, D4, jPer);
        long long eunits = (long long)E * D4;
        int eblocks = (int)((eunits + 255) / 256);
        edge_kernel<<<eblocks, 256, 0, stream>>>((const f4*)edge_attr, edge_index,
                                                 batch_vec, ws, out, E, N, D4);
    }
}

// Round 7
// 65.552 us; speedup vs baseline: 2.2919x; 1.1507x over previous
//
#include <hip/hip_runtime.h>

// out[g,i,j,:] = edge_attr[e] at edge cells (unique, off-diag -> overwrite)
//             + emb_table[1] on in-graph diagonal, emb_table[2] elsewhere.
// A: flat pattern-memset of emb2 over the whole output (memset-shaped;
//    one extra block computes per-graph offsets into ws concurrently).
// B: diag overwrite (one unit per real node) + edge overwrite, one dispatch.

typedef float f4 __attribute__((ext_vector_type(4)));

// grid = fillBlocks + 1. Last block: prep (offs[0..B], offs[B]=total).
// Others: block b writes units [b*256, b*256+256) -> 4KB contiguous.
__global__ __launch_bounds__(256) void fillprep_kernel(
        f4* __restrict__ out, const f4* __restrict__ emb,
        const int* __restrict__ batch, int* __restrict__ offs,
        int TN, int B, int D4, int fillBlocks) {
    if ((int)blockIdx.x == fillBlocks) {
        __shared__ int cnt[1024];
        for (int i = threadIdx.x; i < B; i += 256) cnt[i] = 0;
        __syncthreads();
        for (int v = threadIdx.x; v < TN; v += 256)
            atomicAdd(&cnt[batch[v]], 1);
        __syncthreads();
        if (threadIdx.x == 0) {
            int acc = 0;
            for (int g = 0; g < B; ++g) { offs[g] = acc; acc += cnt[g]; }
            offs[B] = acc;
        }
        return;
    }
    size_t unit = ((size_t)blockIdx.x << 8) + threadIdx.x;
    f4 v2 = emb[2 * D4 + (int)(unit & (D4 - 1))];
    out[unit] = v2;
}

// diag units first (TN*D4: one float4 per real node per d4), then edge units.
__global__ __launch_bounds__(256) void diagedge_kernel(
        const f4* __restrict__ attr, const f4* __restrict__ emb,
        const int* __restrict__ eidx, const int* __restrict__ batch,
        const int* __restrict__ offs, f4* __restrict__ out,
        int E, int N, int TN, int D4, int lg) {
    long long idx = (long long)blockIdx.x * 256 + threadIdx.x;
    long long dUnits = (long long)TN << lg;
    if (idx < dUnits) {
        int n  = (int)(idx >> lg);          // global node id
        int d4 = (int)idx & (D4 - 1);
        int g = batch[n];
        int i = n - offs[g];                // local index (always < counts[g])
        size_t row = (size_t)(g * N + i);
        out[(row * N + i) * D4 + d4] = emb[D4 + d4];
        return;
    }
    idx -= dUnits;
    if (idx < ((long long)E << lg)) {
        int e  = (int)(idx >> lg);
        int d4 = (int)idx & (D4 - 1);
        int s = eidx[e], d = eidx[E + e];
        int g = batch[s];
        int off = offs[g];
        size_t row = (size_t)(g * N + (s - off));
        out[(row * N + (d - off)) * D4 + d4] = attr[((size_t)e << lg) + d4];
    }
}

// ---------------- fallback (R1 structure) ----------------

__global__ void prep_kernel(const int* __restrict__ batch, int* __restrict__ ws,
                            int TN, int B) {
    extern __shared__ int cnt[];
    for (int i = threadIdx.x; i < B; i += blockDim.x) cnt[i] = 0;
    __syncthreads();
    for (int v = threadIdx.x; v < TN; v += blockDim.x)
        atomicAdd(&cnt[batch[v]], 1);
    __syncthreads();
    if (threadIdx.x == 0) {
        int acc = 0;
        for (int g = 0; g < B; ++g) {
            int c = cnt[g];
            ws[g] = acc; ws[B + g] = c; acc += c;
        }
    }
}

__global__ void fill_kernel(f4* __restrict__ out, const f4* __restrict__ emb,
                            const int* __restrict__ counts, int N, int D4, int jPer) {
    int g  = blockIdx.z;
    int i  = blockIdx.y;
    int d4 = threadIdx.x % D4;
    int jj = threadIdx.x / D4;
    int j  = blockIdx.x * jPer + jj;
    if (j >= N) return;
    f4 v1 = emb[D4 + d4];
    f4 v2 = emb[2 * D4 + d4];
    bool diag = (j == i) && (i < counts[g]);
    f4 v = diag ? v1 : v2;
    size_t row = (size_t)(g * N + i);
    out[(row * N + j) * D4 + d4] = v;
}

__global__ void edge_kernel(const f4* __restrict__ attr, const int* __restrict__ eidx,
                            const int* __restrict__ batch, const int* __restrict__ offs,
                            f4* __restrict__ out, int E, int N, int D4) {
    int idx = blockIdx.x * blockDim.x + threadIdx.x;
    if (idx >= E * D4) return;
    int e  = idx / D4;
    int d4 = idx - e * D4;
    int s  = eidx[e];
    int d  = eidx[E + e];
    int g  = batch[s];
    int off = offs[g];
    out[(((size_t)g * N + (s - off)) * N + (d - off)) * D4 + d4] =
        attr[(size_t)e * D4 + d4];
}

extern "C" void kernel_launch(void* const* d_in, const int* in_sizes, int n_in,
                              void* d_out, int out_size, void* d_ws, size_t ws_size,
                              hipStream_t stream) {
    const float* edge_attr  = (const float*)d_in[0];
    const float* emb_table  = (const float*)d_in[1];
    const int*   edge_index = (const int*)d_in[2];
    const int*   batch_vec  = (const int*)d_in[3];

    int D  = in_sizes[1] / 3;                 // emb_table [3, D]
    int E  = in_sizes[2] / 2;                 // edge_index [2, E]
    int TN = in_sizes[3];                     // total nodes
    int D4 = D / 4;
    int N  = (int)((long long)out_size / ((long long)TN * (long long)D));
    int B  = TN / N;

    f4*  out = (f4*)d_out;
    int* ws  = (int*)d_ws;

    long long total4 = (long long)out_size / 4;
    bool pow2D4 = (D4 > 0) && ((D4 & (D4 - 1)) == 0) && D4 <= 256 && (D % 4 == 0);
    bool fast = pow2D4 && (total4 % 256 == 0) && B <= 1024 &&
                (long long)ws_size >= (long long)(B + 1) * 4;

    if (fast) {
        int lg = 0; while ((1 << lg) < D4) ++lg;
        int fillBlocks = (int)(total4 >> 8);
        fillprep_kernel<<<fillBlocks + 1, 256, 0, stream>>>(
            out, (const f4*)emb_table, batch_vec, ws, TN, B, D4, fillBlocks);

        long long tUnits = ((long long)TN << lg) + ((long long)E << lg);
        int bBlocks = (int)((tUnits + 255) / 256);
        diagedge_kernel<<<bBlocks, 256, 0, stream>>>(
            (const f4*)edge_attr, (const f4*)emb_table, edge_index, batch_vec,
            ws, out, E, N, TN, D4, lg);
    } else {
        prep_kernel<<<1, 1024, (size_t)B * sizeof(int), stream>>>(batch_vec, ws, TN, B);
        int jPer = 256 / D4; if (jPer < 1) jPer = 1;
        dim3 fgrid((N + jPer - 1) / jPer, N, B);
        fill_kernel<<<fgrid, 256, 0, stream>>>(out, (const f4*)emb_table,
                                               ws + B, N, D4, jPer);
        long long eunits = (long long)E * D4;
        int eblocks = (int)((eunits + 255) / 256);
        edge_kernel<<<eblocks, 256, 0, stream>>>((const f4*)edge_attr, edge_index,
                                                 batch_vec, ws, out, E, N, D4);
    }
}

// Round 8
// 62.814 us; speedup vs baseline: 2.3918x; 1.0436x over previous
//
#include <hip/hip_runtime.h>

// out[g,i,j,:] = edge_attr[e] at edge cells (unique, off-diag -> overwrite)
//             + emb_table[1] on in-graph diagonal, emb_table[2] elsewhere.
// A: flat pattern-memset of emb2, 4 stores/thread (16KB contiguous per block);
//    one extra block computes per-graph offsets into ws concurrently.
// B: diag overwrite (one unit per real node) + edge overwrite, one dispatch.

typedef float f4 __attribute__((ext_vector_type(4)));

// grid = fillBlocks + 1. Last block: prep (offs[0..B], offs[B]=total).
// Others: block b writes units [b*1024, b*1024+1024) -> 16KB contiguous,
// 4 stores per thread, emb value hoisted (d4 loop-invariant since 256%D4==0).
__global__ __launch_bounds__(256) void fillprep_kernel(
        f4* __restrict__ out, const f4* __restrict__ emb,
        const int* __restrict__ batch, int* __restrict__ offs,
        int TN, int B, int D4, int fillBlocks) {
    if ((int)blockIdx.x == fillBlocks) {
        __shared__ int cnt[1024];
        for (int i = threadIdx.x; i < B; i += 256) cnt[i] = 0;
        __syncthreads();
        for (int v = threadIdx.x; v < TN; v += 256)
            atomicAdd(&cnt[batch[v]], 1);
        __syncthreads();
        if (threadIdx.x == 0) {
            int acc = 0;
            for (int g = 0; g < B; ++g) { offs[g] = acc; acc += cnt[g]; }
            offs[B] = acc;
        }
        return;
    }
    size_t base = ((size_t)blockIdx.x << 10) + threadIdx.x;
    f4 v2 = emb[2 * D4 + (int)(base & (D4 - 1))];
#pragma unroll
    for (int k = 0; k < 4; ++k)
        out[base + (size_t)k * 256] = v2;
}

// diag units first (TN*D4: one float4 per real node per d4), then edge units.
__global__ __launch_bounds__(256) void diagedge_kernel(
        const f4* __restrict__ attr, const f4* __restrict__ emb,
        const int* __restrict__ eidx, const int* __restrict__ batch,
        const int* __restrict__ offs, f4* __restrict__ out,
        int E, int N, int TN, int D4, int lg) {
    long long idx = (long long)blockIdx.x * 256 + threadIdx.x;
    long long dUnits = (long long)TN << lg;
    if (idx < dUnits) {
        int n  = (int)(idx >> lg);          // global node id
        int d4 = (int)idx & (D4 - 1);
        int g = batch[n];
        int i = n - offs[g];                // local index (always < counts[g])
        size_t row = (size_t)(g * N + i);
        out[(row * N + i) * D4 + d4] = emb[D4 + d4];
        return;
    }
    idx -= dUnits;
    if (idx < ((long long)E << lg)) {
        int e  = (int)(idx >> lg);
        int d4 = (int)idx & (D4 - 1);
        int s = eidx[e], d = eidx[E + e];
        int g = batch[s];
        int off = offs[g];
        size_t row = (size_t)(g * N + (s - off));
        out[(row * N + (d - off)) * D4 + d4] = attr[((size_t)e << lg) + d4];
    }
}

// ---------------- fallback (R1 structure) ----------------

__global__ void prep_kernel(const int* __restrict__ batch, int* __restrict__ ws,
                            int TN, int B) {
    extern __shared__ int cnt[];
    for (int i = threadIdx.x; i < B; i += blockDim.x) cnt[i] = 0;
    __syncthreads();
    for (int v = threadIdx.x; v < TN; v += blockDim.x)
        atomicAdd(&cnt[batch[v]], 1);
    __syncthreads();
    if (threadIdx.x == 0) {
        int acc = 0;
        for (int g = 0; g < B; ++g) {
            int c = cnt[g];
            ws[g] = acc; ws[B + g] = c; acc += c;
        }
    }
}

__global__ void fill_kernel(f4* __restrict__ out, const f4* __restrict__ emb,
                            const int* __restrict__ counts, int N, int D4, int jPer) {
    int g  = blockIdx.z;
    int i  = blockIdx.y;
    int d4 = threadIdx.x % D4;
    int jj = threadIdx.x / D4;
    int j  = blockIdx.x * jPer + jj;
    if (j >= N) return;
    f4 v1 = emb[D4 + d4];
    f4 v2 = emb[2 * D4 + d4];
    bool diag = (j == i) && (i < counts[g]);
    f4 v = diag ? v1 : v2;
    size_t row = (size_t)(g * N + i);
    out[(row * N + j) * D4 + d4] = v;
}

__global__ void edge_kernel(const f4* __restrict__ attr, const int* __restrict__ eidx,
                            const int* __restrict__ batch, const int* __restrict__ offs,
                            f4* __restrict__ out, int E, int N, int D4) {
    int idx = blockIdx.x * blockDim.x + threadIdx.x;
    if (idx >= E * D4) return;
    int e  = idx / D4;
    int d4 = idx - e * D4;
    int s  = eidx[e];
    int d  = eidx[E + e];
    int g  = batch[s];
    int off = offs[g];
    out[(((size_t)g * N + (s - off)) * N + (d - off)) * D4 + d4] =
        attr[(size_t)e * D4 + d4];
}

extern "C" void kernel_launch(void* const* d_in, const int* in_sizes, int n_in,
                              void* d_out, int out_size, void* d_ws, size_t ws_size,
                              hipStream_t stream) {
    const float* edge_attr  = (const float*)d_in[0];
    const float* emb_table  = (const float*)d_in[1];
    const int*   edge_index = (const int*)d_in[2];
    const int*   batch_vec  = (const int*)d_in[3];

    int D  = in_sizes[1] / 3;                 // emb_table [3, D]
    int E  = in_sizes[2] / 2;                 // edge_index [2, E]
    int TN = in_sizes[3];                     // total nodes
    int D4 = D / 4;
    int N  = (int)((long long)out_size / ((long long)TN * (long long)D));
    int B  = TN / N;

    f4*  out = (f4*)d_out;
    int* ws  = (int*)d_ws;

    long long total4 = (long long)out_size / 4;
    bool pow2D4 = (D4 > 0) && ((D4 & (D4 - 1)) == 0) && D4 <= 256 && (D % 4 == 0);
    bool fast = pow2D4 && (total4 % 1024 == 0) && B <= 1024 &&
                (long long)ws_size >= (long long)(B + 1) * 4;

    if (fast) {
        int lg = 0; while ((1 << lg) < D4) ++lg;
        int fillBlocks = (int)(total4 >> 10);
        fillprep_kernel<<<fillBlocks + 1, 256, 0, stream>>>(
            out, (const f4*)emb_table, batch_vec, ws, TN, B, D4, fillBlocks);

        long long tUnits = ((long long)TN << lg) + ((long long)E << lg);
        int bBlocks = (int)((tUnits + 255) / 256);
        diagedge_kernel<<<bBlocks, 256, 0, stream>>>(
            (const f4*)edge_attr, (const f4*)emb_table, edge_index, batch_vec,
            ws, out, E, N, TN, D4, lg);
    } else {
        prep_kernel<<<1, 1024, (size_t)B * sizeof(int), stream>>>(batch_vec, ws, TN, B);
        int jPer = 256 / D4; if (jPer < 1) jPer = 1;
        dim3 fgrid((N + jPer - 1) / jPer, N, B);
        fill_kernel<<<fgrid, 256, 0, stream>>>(out, (const f4*)emb_table,
                                               ws + B, N, D4, jPer);
        long long eunits = (long long)E * D4;
        int eblocks = (int)((eunits + 255) / 256);
        edge_kernel<<<eblocks, 256, 0, stream>>>((const f4*)edge_attr, edge_index,
                                                 batch_vec, ws, out, E, N, D4);
    }
}

// Round 9
// 61.870 us; speedup vs baseline: 2.4283x; 1.0153x over previous
//
#include <hip/hip_runtime.h>

// out[g,i,j,:] = edge_attr[e] at edge cells (unique, off-diag -> overwrite)
//             + emb_table[1] on in-graph diagonal, emb_table[2] elsewhere.
// Uniform fast path (TN == B*N, pow2 N/D4): all graphs full -> offs[g]=g*N;
//   A: pure flat pattern-memset of emb2, 8 stores/thread (32KB/block).
//   B: diag overwrite (row = global node id) + edge overwrite, pure arithmetic.
// Generic path: R8 structure (prep block inside fill + offs-based diagedge).

typedef float f4 __attribute__((ext_vector_type(4)));

// ---------------- uniform path ----------------

__global__ __launch_bounds__(256) void fill_u_kernel(
        f4* __restrict__ out, const f4* __restrict__ emb, int D4) {
    size_t base = ((size_t)blockIdx.x << 11) + threadIdx.x;
    f4 v2 = emb[2 * D4 + (int)(base & (D4 - 1))];
#pragma unroll
    for (int k = 0; k < 8; ++k)
        out[base + (size_t)k * 256] = v2;
}

__global__ __launch_bounds__(256) void diagedge_u_kernel(
        const f4* __restrict__ attr, const f4* __restrict__ emb,
        const int* __restrict__ eidx, f4* __restrict__ out,
        int E, int N, int TN, int D4, int lg) {
    long long idx = (long long)blockIdx.x * 256 + threadIdx.x;
    long long dUnits = (long long)TN << lg;
    if (idx < dUnits) {
        int n  = (int)(idx >> lg);          // global node id == global row id
        int d4 = (int)idx & (D4 - 1);
        int i = n & (N - 1);                // local index
        out[((size_t)n * N + i) * D4 + d4] = emb[D4 + d4];
        return;
    }
    idx -= dUnits;
    if (idx < ((long long)E << lg)) {
        int e  = (int)(idx >> lg);
        int d4 = (int)idx & (D4 - 1);
        int s = eidx[e];                    // global src == global row id
        int d = eidx[E + e];
        int dj = d & (N - 1);               // local dst
        out[((size_t)s * N + dj) * D4 + d4] = attr[((size_t)e << lg) + d4];
    }
}

// ---------------- generic fast path (R8) ----------------

__global__ __launch_bounds__(256) void fillprep_kernel(
        f4* __restrict__ out, const f4* __restrict__ emb,
        const int* __restrict__ batch, int* __restrict__ offs,
        int TN, int B, int D4, int fillBlocks) {
    if ((int)blockIdx.x == fillBlocks) {
        __shared__ int cnt[1024];
        for (int i = threadIdx.x; i < B; i += 256) cnt[i] = 0;
        __syncthreads();
        for (int v = threadIdx.x; v < TN; v += 256)
            atomicAdd(&cnt[batch[v]], 1);
        __syncthreads();
        if (threadIdx.x == 0) {
            int acc = 0;
            for (int g = 0; g < B; ++g) { offs[g] = acc; acc += cnt[g]; }
            offs[B] = acc;
        }
        return;
    }
    size_t base = ((size_t)blockIdx.x << 10) + threadIdx.x;
    f4 v2 = emb[2 * D4 + (int)(base & (D4 - 1))];
#pragma unroll
    for (int k = 0; k < 4; ++k)
        out[base + (size_t)k * 256] = v2;
}

__global__ __launch_bounds__(256) void diagedge_kernel(
        const f4* __restrict__ attr, const f4* __restrict__ emb,
        const int* __restrict__ eidx, const int* __restrict__ batch,
        const int* __restrict__ offs, f4* __restrict__ out,
        int E, int N, int TN, int D4, int lg) {
    long long idx = (long long)blockIdx.x * 256 + threadIdx.x;
    long long dUnits = (long long)TN << lg;
    if (idx < dUnits) {
        int n  = (int)(idx >> lg);
        int d4 = (int)idx & (D4 - 1);
        int g = batch[n];
        int i = n - offs[g];
        size_t row = (size_t)(g * N + i);
        out[(row * N + i) * D4 + d4] = emb[D4 + d4];
        return;
    }
    idx -= dUnits;
    if (idx < ((long long)E << lg)) {
        int e  = (int)(idx >> lg);
        int d4 = (int)idx & (D4 - 1);
        int s = eidx[e], d = eidx[E + e];
        int g = batch[s];
        int off = offs[g];
        size_t row = (size_t)(g * N + (s - off));
        out[(row * N + (d - off)) * D4 + d4] = attr[((size_t)e << lg) + d4];
    }
}

// ---------------- fallback (R1 structure) ----------------

__global__ void prep_kernel(const int* __restrict__ batch, int* __restrict__ ws,
                            int TN, int B) {
    extern __shared__ int cnt[];
    for (int i = threadIdx.x; i < B; i += blockDim.x) cnt[i] = 0;
    __syncthreads();
    for (int v = threadIdx.x; v < TN; v += blockDim.x)
        atomicAdd(&cnt[batch[v]], 1);
    __syncthreads();
    if (threadIdx.x == 0) {
        int acc = 0;
        for (int g = 0; g < B; ++g) {
            int c = cnt[g];
            ws[g] = acc; ws[B + g] = c; acc += c;
        }
    }
}

__global__ void fill_kernel(f4* __restrict__ out, const f4* __restrict__ emb,
                            const int* __restrict__ counts, int N, int D4, int jPer) {
    int g  = blockIdx.z;
    int i  = blockIdx.y;
    int d4 = threadIdx.x % D4;
    int jj = threadIdx.x / D4;
    int j  = blockIdx.x * jPer + jj;
    if (j >= N) return;
    f4 v1 = emb[D4 + d4];
    f4 v2 = emb[2 * D4 + d4];
    bool diag = (j == i) && (i < counts[g]);
    f4 v = diag ? v1 : v2;
    size_t row = (size_t)(g * N + i);
    out[(row * N + j) * D4 + d4] = v;
}

__global__ void edge_kernel(const f4* __restrict__ attr, const int* __restrict__ eidx,
                            const int* __restrict__ batch, const int* __restrict__ offs,
                            f4* __restrict__ out, int E, int N, int D4) {
    int idx = blockIdx.x * blockDim.x + threadIdx.x;
    if (idx >= E * D4) return;
    int e  = idx / D4;
    int d4 = idx - e * D4;
    int s  = eidx[e];
    int d  = eidx[E + e];
    int g  = batch[s];
    int off = offs[g];
    out[(((size_t)g * N + (s - off)) * N + (d - off)) * D4 + d4] =
        attr[(size_t)e * D4 + d4];
}

extern "C" void kernel_launch(void* const* d_in, const int* in_sizes, int n_in,
                              void* d_out, int out_size, void* d_ws, size_t ws_size,
                              hipStream_t stream) {
    const float* edge_attr  = (const float*)d_in[0];
    const float* emb_table  = (const float*)d_in[1];
    const int*   edge_index = (const int*)d_in[2];
    const int*   batch_vec  = (const int*)d_in[3];

    int D  = in_sizes[1] / 3;                 // emb_table [3, D]
    int E  = in_sizes[2] / 2;                 // edge_index [2, E]
    int TN = in_sizes[3];                     // total nodes
    int D4 = D / 4;
    int N  = (int)((long long)out_size / ((long long)TN * (long long)D));
    int B  = TN / N;

    f4*  out = (f4*)d_out;
    int* ws  = (int*)d_ws;

    auto ispow2 = [](int x) { return x > 0 && (x & (x - 1)) == 0; };
    long long total4 = (long long)out_size / 4;
    bool pow2D4 = ispow2(D4) && D4 <= 256 && (D % 4 == 0);
    int lg = 0; while ((1 << lg) < D4) ++lg;

    bool uniform = pow2D4 && ispow2(N) && ((long long)B * N == TN) &&
                   (total4 % 2048 == 0);

    if (uniform) {
        int fillBlocks = (int)(total4 >> 11);
        fill_u_kernel<<<fillBlocks, 256, 0, stream>>>(out, (const f4*)emb_table, D4);

        long long tUnits = ((long long)TN << lg) + ((long long)E << lg);
        int bBlocks = (int)((tUnits + 255) / 256);
        diagedge_u_kernel<<<bBlocks, 256, 0, stream>>>(
            (const f4*)edge_attr, (const f4*)emb_table, edge_index, out,
            E, N, TN, D4, lg);
        return;
    }

    bool fast = pow2D4 && (total4 % 1024 == 0) && B <= 1024 &&
                (long long)ws_size >= (long long)(B + 1) * 4;

    if (fast) {
        int fillBlocks = (int)(total4 >> 10);
        fillprep_kernel<<<fillBlocks + 1, 256, 0, stream>>>(
            out, (const f4*)emb_table, batch_vec, ws, TN, B, D4, fillBlocks);

        long long tUnits = ((long long)TN << lg) + ((long long)E << lg);
        int bBlocks = (int)((tUnits + 255) / 256);
        diagedge_kernel<<<bBlocks, 256, 0, stream>>>(
            (const f4*)edge_attr, (const f4*)emb_table, edge_index, batch_vec,
            ws, out, E, N, TN, D4, lg);
    } else {
        prep_kernel<<<1, 1024, (size_t)B * sizeof(int), stream>>>(batch_vec, ws, TN, B);
        int jPer = 256 / D4; if (jPer < 1) jPer = 1;
        dim3 fgrid((N + jPer - 1) / jPer, N, B);
        fill_kernel<<<fgrid, 256, 0, stream>>>(out, (const f4*)emb_table,
                                               ws + B, N, D4, jPer);
        long long eunits = (long long)E * D4;
        int eblocks = (int)((eunits + 255) / 256);
        edge_kernel<<<eblocks, 256, 0, stream>>>((const f4*)edge_attr, edge_index,
                                                 batch_vec, ws, out, E, N, D4);
    }
}

// Round 10
// 61.360 us; speedup vs baseline: 2.4485x; 1.0083x over previous
//
#include <hip/hip_runtime.h>

// out[g,i,j,:] = edge_attr[e] at edge cells (unique, off-diag -> overwrite)
//             + emb_table[1] on in-graph diagonal, emb_table[2] elsewhere.
// Uniform fast path (TN == B*N, pow2 N/D4): offs[g]=g*N.
//   A: persistent grid-stride fill (2048 blocks, 8 stores/thread/iter),
//      diag computed inline from the flat index (no counts/offs loads).
//   B: edge overwrite only (pure arithmetic addressing).
// Generic/fallback paths preserved from R8/R1.

typedef float f4 __attribute__((ext_vector_type(4)));

// ---------------- uniform path ----------------

__global__ __launch_bounds__(256) void fill_u_kernel(
        f4* __restrict__ out, const f4* __restrict__ emb,
        long long total4, int D4, int lg, int lgN) {
    long long base0 = ((long long)blockIdx.x << 11) + threadIdx.x;
    long long stride = (long long)gridDim.x << 11;
    int d4 = (int)base0 & (D4 - 1);
    f4 v1 = emb[D4 + d4];          // diag value
    f4 v2 = emb[2 * D4 + d4];      // background value
    int Nm1 = (1 << lgN) - 1;
    for (long long base = base0; base < total4; base += stride) {
#pragma unroll
        for (int k = 0; k < 8; ++k) {
            long long u = base + (long long)(k << 8);
            long long c = u >> lg;                 // cell index = rowg*N + j
            int j = (int)c & Nm1;
            int i = (int)(c >> lgN) & Nm1;
            out[u] = (j == i) ? v1 : v2;
        }
    }
}

__global__ __launch_bounds__(256) void edge_u_kernel(
        const f4* __restrict__ attr, const int* __restrict__ eidx,
        f4* __restrict__ out, int E, int N, int D4, int lg) {
    long long idx = (long long)blockIdx.x * 256 + threadIdx.x;
    if (idx < ((long long)E << lg)) {
        int e  = (int)(idx >> lg);
        int d4 = (int)idx & (D4 - 1);
        int s = eidx[e];                    // global src == global row id
        int d = eidx[E + e];
        int dj = d & (N - 1);               // local dst
        out[(((size_t)s * N + dj) << lg) + d4] = attr[((size_t)e << lg) + d4];
    }
}

// ---------------- generic fast path (R8) ----------------

__global__ __launch_bounds__(256) void fillprep_kernel(
        f4* __restrict__ out, const f4* __restrict__ emb,
        const int* __restrict__ batch, int* __restrict__ offs,
        int TN, int B, int D4, int fillBlocks) {
    if ((int)blockIdx.x == fillBlocks) {
        __shared__ int cnt[1024];
        for (int i = threadIdx.x; i < B; i += 256) cnt[i] = 0;
        __syncthreads();
        for (int v = threadIdx.x; v < TN; v += 256)
            atomicAdd(&cnt[batch[v]], 1);
        __syncthreads();
        if (threadIdx.x == 0) {
            int acc = 0;
            for (int g = 0; g < B; ++g) { offs[g] = acc; acc += cnt[g]; }
            offs[B] = acc;
        }
        return;
    }
    size_t base = ((size_t)blockIdx.x << 10) + threadIdx.x;
    f4 v2 = emb[2 * D4 + (int)(base & (D4 - 1))];
#pragma unroll
    for (int k = 0; k < 4; ++k)
        out[base + (size_t)k * 256] = v2;
}

__global__ __launch_bounds__(256) void diagedge_kernel(
        const f4* __restrict__ attr, const f4* __restrict__ emb,
        const int* __restrict__ eidx, const int* __restrict__ batch,
        const int* __restrict__ offs, f4* __restrict__ out,
        int E, int N, int TN, int D4, int lg) {
    long long idx = (long long)blockIdx.x * 256 + threadIdx.x;
    long long dUnits = (long long)TN << lg;
    if (idx < dUnits) {
        int n  = (int)(idx >> lg);
        int d4 = (int)idx & (D4 - 1);
        int g = batch[n];
        int i = n - offs[g];
        size_t row = (size_t)(g * N + i);
        out[(row * N + i) * D4 + d4] = emb[D4 + d4];
        return;
    }
    idx -= dUnits;
    if (idx < ((long long)E << lg)) {
        int e  = (int)(idx >> lg);
        int d4 = (int)idx & (D4 - 1);
        int s = eidx[e], d = eidx[E + e];
        int g = batch[s];
        int off = offs[g];
        size_t row = (size_t)(g * N + (s - off));
        out[(row * N + (d - off)) * D4 + d4] = attr[((size_t)e << lg) + d4];
    }
}

// ---------------- fallback (R1 structure) ----------------

__global__ void prep_kernel(const int* __restrict__ batch, int* __restrict__ ws,
                            int TN, int B) {
    extern __shared__ int cnt[];
    for (int i = threadIdx.x; i < B; i += blockDim.x) cnt[i] = 0;
    __syncthreads();
    for (int v = threadIdx.x; v < TN; v += blockDim.x)
        atomicAdd(&cnt[batch[v]], 1);
    __syncthreads();
    if (threadIdx.x == 0) {
        int acc = 0;
        for (int g = 0; g < B; ++g) {
            int c = cnt[g];
            ws[g] = acc; ws[B + g] = c; acc += c;
        }
    }
}

__global__ void fill_kernel(f4* __restrict__ out, const f4* __restrict__ emb,
                            const int* __restrict__ counts, int N, int D4, int jPer) {
    int g  = blockIdx.z;
    int i  = blockIdx.y;
    int d4 = threadIdx.x % D4;
    int jj = threadIdx.x / D4;
    int j  = blockIdx.x * jPer + jj;
    if (j >= N) return;
    f4 v1 = emb[D4 + d4];
    f4 v2 = emb[2 * D4 + d4];
    bool diag = (j == i) && (i < counts[g]);
    f4 v = diag ? v1 : v2;
    size_t row = (size_t)(g * N + i);
    out[(row * N + j) * D4 + d4] = v;
}

__global__ void edge_kernel(const f4* __restrict__ attr, const int* __restrict__ eidx,
                            const int* __restrict__ batch, const int* __restrict__ offs,
                            f4* __restrict__ out, int E, int N, int D4) {
    int idx = blockIdx.x * blockDim.x + threadIdx.x;
    if (idx >= E * D4) return;
    int e  = idx / D4;
    int d4 = idx - e * D4;
    int s  = eidx[e];
    int d  = eidx[E + e];
    int g  = batch[s];
    int off = offs[g];
    out[(((size_t)g * N + (s - off)) * N + (d - off)) * D4 + d4] =
        attr[(size_t)e * D4 + d4];
}

extern "C" void kernel_launch(void* const* d_in, const int* in_sizes, int n_in,
                              void* d_out, int out_size, void* d_ws, size_t ws_size,
                              hipStream_t stream) {
    const float* edge_attr  = (const float*)d_in[0];
    const float* emb_table  = (const float*)d_in[1];
    const int*   edge_index = (const int*)d_in[2];
    const int*   batch_vec  = (const int*)d_in[3];

    int D  = in_sizes[1] / 3;                 // emb_table [3, D]
    int E  = in_sizes[2] / 2;                 // edge_index [2, E]
    int TN = in_sizes[3];                     // total nodes
    int D4 = D / 4;
    int N  = (int)((long long)out_size / ((long long)TN * (long long)D));
    int B  = TN / N;

    f4*  out = (f4*)d_out;
    int* ws  = (int*)d_ws;

    auto ispow2 = [](int x) { return x > 0 && (x & (x - 1)) == 0; };
    long long total4 = (long long)out_size / 4;
    bool pow2D4 = ispow2(D4) && D4 <= 256 && (D % 4 == 0);
    int lg = 0; while ((1 << lg) < D4) ++lg;
    int lgN = 0; while ((1 << lgN) < N) ++lgN;

    bool uniform = pow2D4 && ispow2(N) && ((long long)B * N == TN) &&
                   (total4 % 2048 == 0);

    if (uniform) {
        long long chunks = total4 >> 11;
        int fgrid = (int)(chunks < 2048 ? chunks : 2048);
        fill_u_kernel<<<fgrid, 256, 0, stream>>>(out, (const f4*)emb_table,
                                                 total4, D4, lg, lgN);

        long long eUnits = (long long)E << lg;
        int bBlocks = (int)((eUnits + 255) / 256);
        edge_u_kernel<<<bBlocks, 256, 0, stream>>>(
            (const f4*)edge_attr, edge_index, out, E, N, D4, lg);
        return;
    }

    bool fast = pow2D4 && (total4 % 1024 == 0) && B <= 1024 &&
                (long long)ws_size >= (long long)(B + 1) * 4;

    if (fast) {
        int fillBlocks = (int)(total4 >> 10);
        fillprep_kernel<<<fillBlocks + 1, 256, 0, stream>>>(
            out, (const f4*)emb_table, batch_vec, ws, TN, B, D4, fillBlocks);

        long long tUnits = ((long long)TN << lg) + ((long long)E << lg);
        int bBlocks = (int)((tUnits + 255) / 256);
        diagedge_kernel<<<bBlocks, 256, 0, stream>>>(
            (const f4*)edge_attr, (const f4*)emb_table, edge_index, batch_vec,
            ws, out, E, N, TN, D4, lg);
    } else {
        prep_kernel<<<1, 1024, (size_t)B * sizeof(int), stream>>>(batch_vec, ws, TN, B);
        int jPer = 256 / D4; if (jPer < 1) jPer = 1;
        dim3 fgrid((N + jPer - 1) / jPer, N, B);
        fill_kernel<<<fgrid, 256, 0, stream>>>(out, (const f4*)emb_table,
                                               ws + B, N, D4, jPer);
        long long eunits = (long long)E * D4;
        int eblocks = (int)((eunits + 255) / 256);
        edge_kernel<<<eblocks, 256, 0, stream>>>((const f4*)edge_attr, edge_index,
                                                 batch_vec, ws, out, E, N, D4);
    }
}